// Round 13
// baseline (213.100 us; speedup 1.0000x reference)
//
#include <hip/hip_runtime.h>

// Problem constants (from reference): T=1024, B=128, C=256, L=64
#define NEG (-1e30f)
#define LOG2E 1.4426950408889634f
#define LN2 0.69314718055994531f
constexpr int T = 1024;
constexpr int B = 128;
constexpr int C = 256;
constexpr int L = 64;
constexpr int ENT_GRID = 1024;  // entropy blocks (blocks [0, ENT_GRID))
constexpr int K = 16;           // t-steps per register-staged chunk
// R13 = REVERT to the R8 kernel (passed, absmax 0.0, 211.3 us).
// Forward-backward split: ll = lse_s(alpha_m[s] + beta_m[s] - lp_m[s]) at any
// m. Wave0: alpha t=1..m; Wave1: beta t=len-2..m. Serial length <=512 steps.
// Staging: 17 named-scalar regs/chunk (no alloca), double-buffered, inline-asm
// loads + owned s_waitcnt vmcnt(17).
// R10-R12 linear-domain DP (probability semiring + pow2 rescale) failed 3x
// with an unidentified numeric/HW interaction (leading suspect: denormal-
// flush clipping of states >~143 nats below wave max; alpha spread across
// 129 states reaches ~100-140 nats). Two independent RESCALE reductions gave
// DIFFERENT wrong answers -> abandoned per pre-declared decision rule.

#if __has_builtin(__builtin_amdgcn_exp2f)
__device__ __forceinline__ float fexp2(float x) { return __builtin_amdgcn_exp2f(x); }
#else
__device__ __forceinline__ float fexp2(float x) { return __expf(x * LN2); }
#endif
#if __has_builtin(__builtin_amdgcn_logf)
__device__ __forceinline__ float flog2(float x) { return __builtin_amdgcn_logf(x); }
#else
__device__ __forceinline__ float flog2(float x) { return __logf(x) * LOG2E; }
#endif

__device__ __forceinline__ float dpp_shr1(float x, float oldv) {
  // wave_shr:1 -- lane i gets lane i-1's x; lane 0 keeps `oldv`. [proven R8]
  return __int_as_float(__builtin_amdgcn_update_dpp(
      __float_as_int(oldv), __float_as_int(x), 0x138, 0xF, 0xF, false));
}
__device__ __forceinline__ float dpp_shl1(float x, float oldv) {
  // wave_shl:1 -- lane i gets lane i+1's x; lane 63 keeps `oldv`. [proven R8]
  return __int_as_float(__builtin_amdgcn_update_dpp(
      __float_as_int(oldv), __float_as_int(x), 0x130, 0xF, 0xF, false));
}
// lse2 via max+log1p-style: 1 exp + 1 log (saves 1 exp vs 2-exp form).
__device__ __forceinline__ float lse2(float a, float b) {
  return fmaxf(a, b) + flog2(1.f + fexp2(-fabsf(a - b)));
}

// 2x17 staging registers as NAMED scalars (no alloca!): P0..P15 labels, Pb blank.
#define DECL17(P)                                                           \
  float P##0, P##1, P##2, P##3, P##4, P##5, P##6, P##7, P##8, P##9, P##10,  \
      P##11, P##12, P##13, P##14, P##15, P##b;

// Byte offsets: t*B*C*4 = t<<17; labBase = b<<10 | cls<<2; blkBase = b<<10.
#define LOADF(P, c_, k_)                                                    \
  {                                                                         \
    const int t_ = min(1 + (c_)*K + k_, m); /* clamp: addr ok, unused */    \
    const unsigned off_ = labBase + ((unsigned)t_ << 17);                   \
    asm volatile("global_load_dword %0, %1, %2"                             \
                 : "=v"(P##k_) : "v"(off_), "s"(lp));                       \
  }
#define LOADB(P, c_, k_)                                                    \
  {                                                                         \
    const int t_ = max(len - 2 - ((c_)*K + k_), 0);                         \
    const unsigned off_ = labBase + ((unsigned)t_ << 17);                   \
    asm volatile("global_load_dword %0, %1, %2"                             \
                 : "=v"(P##k_) : "v"(off_), "s"(lp));                       \
  }
#define ISSUEF(P, c_)                                                       \
  do {                                                                      \
    LOADF(P, c_, 0) LOADF(P, c_, 1) LOADF(P, c_, 2) LOADF(P, c_, 3)         \
    LOADF(P, c_, 4) LOADF(P, c_, 5) LOADF(P, c_, 6) LOADF(P, c_, 7)         \
    LOADF(P, c_, 8) LOADF(P, c_, 9) LOADF(P, c_, 10) LOADF(P, c_, 11)       \
    LOADF(P, c_, 12) LOADF(P, c_, 13) LOADF(P, c_, 14) LOADF(P, c_, 15)     \
    {                                                                       \
      const int tb_ = min(1 + (c_)*K + lane, m);                            \
      const unsigned offb_ = blkBase + ((unsigned)tb_ << 17);               \
      asm volatile("global_load_dword %0, %1, %2"                           \
                   : "=v"(P##b) : "v"(offb_), "s"(lp));                     \
    }                                                                       \
  } while (0)
#define ISSUEB(P, c_)                                                       \
  do {                                                                      \
    LOADB(P, c_, 0) LOADB(P, c_, 1) LOADB(P, c_, 2) LOADB(P, c_, 3)         \
    LOADB(P, c_, 4) LOADB(P, c_, 5) LOADB(P, c_, 6) LOADB(P, c_, 7)         \
    LOADB(P, c_, 8) LOADB(P, c_, 9) LOADB(P, c_, 10) LOADB(P, c_, 11)       \
    LOADB(P, c_, 12) LOADB(P, c_, 13) LOADB(P, c_, 14) LOADB(P, c_, 15)     \
    {                                                                       \
      const int tb_ = max(len - 2 - (c_)*K - lane, 0);                      \
      const unsigned offb_ = blkBase + ((unsigned)tb_ << 17);               \
      asm volatile("global_load_dword %0, %1, %2"                           \
                   : "=v"(P##b) : "v"(offb_), "s"(lp));                     \
    }                                                                       \
  } while (0)

// "+v" ties REDEFINE the staging regs so no use can float above the wait.
#define WAITTIE(P)                                                          \
  asm volatile("s_waitcnt vmcnt(17)"                                        \
               : "+v"(P##0), "+v"(P##1), "+v"(P##2), "+v"(P##3),            \
                 "+v"(P##4), "+v"(P##5), "+v"(P##6), "+v"(P##7),            \
                 "+v"(P##8), "+v"(P##9), "+v"(P##10), "+v"(P##11),          \
                 "+v"(P##12), "+v"(P##13), "+v"(P##14), "+v"(P##15),        \
                 "+v"(P##b))

// Forward step (log2 domain). a0=alpha[0] (uniform); lane i: o=alpha[2i+1],
// v=alpha[2i+2].
#define STEPF(P, k_)                                                        \
  if (k_ < kend_) {                                                         \
    const float sb_ = __int_as_float(                                       \
        __builtin_amdgcn_readlane(__float_as_int(blsc_), k_));              \
    const float lw_ = P##k_ * LOG2E;                                        \
    const float ev2_ = dpp_shr1(v, a0);  /* alpha[2i]   */                  \
    const float od2_ = dpp_shr1(o, NEG); /* alpha[2i-1] */                  \
    const float p2_ = sameAsPrev ? NEG : od2_;                              \
    const float m1_ = fmaxf(o, fmaxf(ev2_, p2_));                           \
    const float s1_ =                                                       \
        fexp2(o - m1_) + fexp2(ev2_ - m1_) + fexp2(p2_ - m1_);              \
    const float no_ = m1_ + flog2(s1_) + lw_;                               \
    const float nv_ = lse2(v, o) + sb_;                                     \
    a0 += sb_;                                                              \
    o = no_;                                                                \
    v = nv_;                                                                \
  }
// Backward step. a0b=beta[128] (uniform); lane j: ob=beta[2j+1], eb=beta[2j].
//   ob' = lse(ob, eb@(j+1) [j=63 -> a0b], [allowB] ob@(j+1)) + lpl_j
//   eb' = lse(eb, ob) + lpb     a0b' = a0b + lpb
#define STEPB(P, k_)                                                        \
  if (k_ < kend_) {                                                         \
    const float sb_ = __int_as_float(                                       \
        __builtin_amdgcn_readlane(__float_as_int(blsc_), k_));              \
    const float lw_ = P##k_ * LOG2E;                                        \
    const float es_ = dpp_shl1(eb, a0b); /* beta[2j+2]; lane63 -> beta[128] */\
    const float os_ = dpp_shl1(ob, NEG); /* beta[2j+3] */                   \
    const float p2_ = allowB ? os_ : NEG;                                   \
    const float m1_ = fmaxf(ob, fmaxf(es_, p2_));                           \
    const float s1_ =                                                       \
        fexp2(ob - m1_) + fexp2(es_ - m1_) + fexp2(p2_ - m1_);              \
    const float no_ = m1_ + flog2(s1_) + lw_;                               \
    const float ne_ = lse2(eb, ob) + sb_;                                   \
    a0b += sb_;                                                             \
    ob = no_;                                                               \
    eb = ne_;                                                               \
  }

#define COMPUTEF(P, c_)                                                     \
  do {                                                                      \
    const float blsc_ = (P##b)*LOG2E;                                       \
    const int kend_ = stepsN - (c_)*K;                                      \
    STEPF(P, 0) STEPF(P, 1) STEPF(P, 2) STEPF(P, 3) STEPF(P, 4) STEPF(P, 5) \
    STEPF(P, 6) STEPF(P, 7) STEPF(P, 8) STEPF(P, 9) STEPF(P, 10)            \
    STEPF(P, 11) STEPF(P, 12) STEPF(P, 13) STEPF(P, 14) STEPF(P, 15)        \
  } while (0)
#define COMPUTEB(P, c_)                                                     \
  do {                                                                      \
    const float blsc_ = (P##b)*LOG2E;                                       \
    const int kend_ = stepsN - (c_)*K;                                      \
    STEPB(P, 0) STEPB(P, 1) STEPB(P, 2) STEPB(P, 3) STEPB(P, 4) STEPB(P, 5) \
    STEPB(P, 6) STEPB(P, 7) STEPB(P, 8) STEPB(P, 9) STEPB(P, 10)            \
    STEPB(P, 11) STEPB(P, 12) STEPB(P, 13) STEPB(P, 14) STEPB(P, 15)        \
  } while (0)

// ---------------------------------------------------------------------------
__global__ __launch_bounds__(256, 1) void k_fused(
    const float* __restrict__ lp, const int* __restrict__ targets,
    const int* __restrict__ in_len, const int* __restrict__ tg_len,
    float* __restrict__ ent_part, float* __restrict__ nll_out) {
  __shared__ float wsum[4];
  __shared__ float Ast[129], Bst[129], red[4];
  const int tid = threadIdx.x;

  if (blockIdx.x < ENT_GRID) {
    // ---------------- entropy path ----------------
    const size_t N4 = (size_t)T * B * C / 4;
    const float4* lp4 = (const float4*)lp;
    const size_t stride = (size_t)ENT_GRID * 256;
    float a0 = 0.f, a1 = 0.f, a2 = 0.f, a3 = 0.f;
    for (size_t i = (size_t)blockIdx.x * 256 + tid; i < N4; i += stride) {
      const float4 vv = lp4[i];
      a0 += vv.x * __expf(vv.x);
      a1 += vv.y * __expf(vv.y);
      a2 += vv.z * __expf(vv.z);
      a3 += vv.w * __expf(vv.w);
    }
    float ent = (a0 + a1) + (a2 + a3);
    for (int off = 32; off > 0; off >>= 1) ent += __shfl_down(ent, off, 64);
    if ((tid & 63) == 0) wsum[tid >> 6] = ent;
    __syncthreads();
    if (tid == 0) ent_part[blockIdx.x] = wsum[0] + wsum[1] + wsum[2] + wsum[3];
    return;
  }

  // ---------------- CTC path: wave0 = alpha, wave1 = beta ----------------
  if (tid >= 128) return;
  const int b = blockIdx.x - ENT_GRID;
  const int wave = tid >> 6;
  const int lane = tid & 63;
  const int len = in_len[b];        // [512, 1024]
  const int tl = tg_len[b];         // [32, 64]
  const int m = (len - 1) >> 1;     // meeting point

  const int cls = targets[b * L + lane];
  const unsigned labBase = ((unsigned)b << 10) + ((unsigned)cls << 2);
  const unsigned blkBase = ((unsigned)b << 10);

  DECL17(X)
  DECL17(Y)

  if (wave == 0) {
    // ======== alpha: t = 1..m ========
    const int stepsN = m;
    const int nch = (stepsN + K - 1) / K;
    const int prevc = (lane == 0) ? -1 : targets[b * L + lane - 1];
    const bool sameAsPrev = (cls == prevc);
    const float lpb0 = lp[(size_t)b * C];
    const float lpl0 = lp[(size_t)b * C + cls];
    float a0 = lpb0 * LOG2E;
    float o = (lane == 0) ? lpl0 * LOG2E : NEG;
    float v = NEG;
    asm volatile("s_waitcnt vmcnt(0) lgkmcnt(0)" ::: "memory");
    ISSUEF(X, 0);
    int c = 0;
    for (;;) {
      ISSUEF(Y, c + 1);
      WAITTIE(X);
      COMPUTEF(X, c);
      ++c;
      if (c == nch) break;
      ISSUEF(X, c + 1);
      WAITTIE(Y);
      COMPUTEF(Y, c);
      ++c;
      if (c == nch) break;
    }
    asm volatile("s_waitcnt vmcnt(0)" ::: "memory");
    if (lane == 0) Ast[0] = a0;
    Ast[2 * lane + 1] = o;
    Ast[2 * lane + 2] = v;
  } else {
    // ======== beta: init at t=len-1, steps t = len-2 .. m ========
    const int stepsN = len - 1 - m;
    const int nch = (stepsN + K - 1) / K;
    const int nxtc = targets[b * L + min(lane + 1, L - 1)];
    const bool allowB = (lane < 63) && (nxtc != cls);
    const size_t rowE = (size_t)(len - 1) * (B * C) + (size_t)b * C;
    const float lpbE = lp[rowE] * LOG2E;
    const float lplE = lp[rowE + cls] * LOG2E;
    float a0b = (tl == L) ? lpbE : NEG;                  // beta[128]
    float ob = (lane == tl - 1) ? lplE : NEG;            // beta[2tl-1]
    float eb = (lane == tl && tl < L) ? lpbE : NEG;      // beta[2tl]
    asm volatile("s_waitcnt vmcnt(0) lgkmcnt(0)" ::: "memory");
    ISSUEB(X, 0);
    int c = 0;
    for (;;) {
      ISSUEB(Y, c + 1);
      WAITTIE(X);
      COMPUTEB(X, c);
      ++c;
      if (c == nch) break;
      ISSUEB(X, c + 1);
      WAITTIE(Y);
      COMPUTEB(Y, c);
      ++c;
      if (c == nch) break;
    }
    asm volatile("s_waitcnt vmcnt(0)" ::: "memory");
    if (lane == 0) Bst[128] = a0b;
    Bst[2 * lane + 1] = ob;
    Bst[2 * lane] = eb;
  }
  __syncthreads();

  // ---- combine: ll = lse_s(alpha_m[s] + beta_m[s] - lp_m[s]) over 129 s ----
  const size_t rowM = (size_t)m * (B * C) + (size_t)b * C;
  const int scls = (tid & 1) ? targets[b * L + (tid >> 1)] : 0;
  float val = Ast[tid] + Bst[tid] - lp[rowM + scls] * LOG2E;
  if (tid == 0) {
    const float v128 = Ast[128] + Bst[128] - lp[rowM] * LOG2E;
    const float mm = fmaxf(val, v128);
    val = mm + flog2(fexp2(val - mm) + fexp2(v128 - mm));
  }
  float mx = val;
  for (int off = 32; off > 0; off >>= 1)
    mx = fmaxf(mx, __shfl_xor(mx, off, 64));
  if (lane == 0) red[wave] = mx;
  __syncthreads();
  mx = fmaxf(red[0], red[1]);
  float ex = fexp2(val - mx);
  for (int off = 32; off > 0; off >>= 1) ex += __shfl_xor(ex, off, 64);
  if (lane == 0) red[2 + wave] = ex;
  __syncthreads();
  if (tid == 0) {
    const float ll = (mx + flog2(red[2] + red[3])) * LN2;
    float nll = -ll;
    if (nll > 1e29f) nll = 0.f;  // zero_infinity
    nll_out[b] = nll;
  }
}

// ---------------------------------------------------------------------------
__global__ __launch_bounds__(256) void k_final(
    const float* __restrict__ ent_part, const float* __restrict__ nll,
    float* __restrict__ out) {
  const int tid = threadIdx.x;
  float s = 0.f;
  for (int i = tid; i < ENT_GRID; i += 256) s += ent_part[i];
  float n = (tid < B) ? nll[tid] : 0.f;
  for (int off = 32; off > 0; off >>= 1) {
    s += __shfl_down(s, off, 64);
    n += __shfl_down(n, off, 64);
  }
  __shared__ float ss[4], nn[4];
  if ((tid & 63) == 0) { ss[tid >> 6] = s; nn[tid >> 6] = n; }
  __syncthreads();
  if (tid == 0) {
    const float ent_sum = ss[0] + ss[1] + ss[2] + ss[3];
    const float nll_sum = nn[0] + nn[1] + nn[2] + nn[3];
    const float ctc_mean = nll_sum / (float)B;
    const float smooth = ent_sum / (float)(T * B);  // = -entropy.mean()
    out[0] = 0.9f * ctc_mean + 0.1f * smooth;
  }
}

extern "C" void kernel_launch(void* const* d_in, const int* in_sizes, int n_in,
                              void* d_out, int out_size, void* d_ws, size_t ws_size,
                              hipStream_t stream) {
  const float* lp      = (const float*)d_in[0];  // [T,B,C] f32
  const int*   targets = (const int*)d_in[1];    // [B,L] i32
  const int*   in_len  = (const int*)d_in[2];    // [B] i32
  const int*   tg_len  = (const int*)d_in[3];    // [B] i32
  float* out = (float*)d_out;
  float* ws  = (float*)d_ws;

  float* ent_part = ws;             // [1024]
  float* nllb     = ws + ENT_GRID;  // [128]

  k_fused<<<ENT_GRID + B, 256, 0, stream>>>(lp, targets, in_len, tg_len,
                                            ent_part, nllb);
  k_final<<<1, 256, 0, stream>>>(ent_part, nllb, out);
}